// Round 6
// baseline (165.735 us; speedup 1.0000x reference)
//
#include <hip/hip_runtime.h>
#include <hip/hip_bf16.h>
#include <math.h>

// Q=4096, N=50000, D=5, L=2
// t[q][n] = 2g*(x.r) - g|x|^2 - g|r|^2, g = log2e/(2 sigma^2);  s = 2^t
// K=8 augmented dot on MFMA pipe, split-bf16 (hi+lo) packed into K=32:
//   A32 = [Ah|Ah|Al|0], B32 = [Bh|Bl|Bh|0] => Ah.Bh + Ah.Bl + Al.Bh
#define QTOT   4096
#define NTOT   50000
#define NTILES 3125            // 50000/16
#define NS     64              // n-splits -> 4096 waves = 4 blocks/CU
#define ACCN   (3 * QTOT)
#define MAINBLOCKS 1024

// ws layout (bytes)
#define BOFF   0u                          // B: [ntile][2][16][8 bf16] = 512 B/tile
#define BSIZE  (3125u * 512u)
#define AOFF   (BOFF + BSIZE)              // A: [q][2][8 bf16] = 32 B/q
#define ASIZE  (4096u * 32u)
#define ZOFF   (AOFF + ASIZE)              // 256 B zero block
#define ACCOFF (ZOFF + 256u)               // 3*Q fp32
#define DONEOFF (ACCOFF + ACCN * 4u)       // 1 u32 completion counter

typedef unsigned short ushort_t;
typedef short  s16x8 __attribute__((ext_vector_type(8)));
typedef float  f32x4 __attribute__((ext_vector_type(4)));
typedef float  f2    __attribute__((ext_vector_type(2)));

#if __has_builtin(__builtin_amdgcn_exp2f)
#define EXP2F(x) __builtin_amdgcn_exp2f(x)
#else
#define EXP2F(x) exp2f(x)
#endif

static __device__ __forceinline__ f2 fma2(f2 a, f2 b, f2 c) {
#if __has_builtin(__builtin_elementwise_fma)
    return __builtin_elementwise_fma(a, b, c);
#else
    f2 r; r.x = fmaf(a.x, b.x, c.x); r.y = fmaf(a.y, b.y, c.y); return r;
#endif
}

static __device__ __forceinline__ void bsplit(float f, ushort_t& h, ushort_t& l) {
    __hip_bfloat16 hb = __float2bfloat16(f);
    float hf = __bfloat162float(hb);
    __hip_bfloat16 lb = __float2bfloat16(f - hf);
    h = *reinterpret_cast<ushort_t*>(&hb);
    l = *reinterpret_cast<ushort_t*>(&lb);
}

__global__ __launch_bounds__(256) void sknn_prep(
    const float* __restrict__ rss, const float* __restrict__ Radio,
    const float* __restrict__ sigma, char* __restrict__ ws)
{
    const int p = blockIdx.x * 256 + threadIdx.x;
    const float sg = sigma[0];
    const float g  = 1.4426950408889634f / (2.0f * sg * sg);
    const float g2 = 2.0f * g;

    if (p < NTOT) {
        float b[8]; float rr = 0.f;
        #pragma unroll
        for (int d = 0; d < 5; ++d) { float r = Radio[p*5+d]; b[d] = g2*r; rr += r*r; }
        b[5] = 1.0f; b[6] = -g * rr; b[7] = 0.0f;
        union { ushort_t u[8]; f32x4 v; } hi, lo;
        #pragma unroll
        for (int k = 0; k < 8; ++k) bsplit(b[k], hi.u[k], lo.u[k]);
        const int nt = p >> 4, nsub = p & 15;
        *(f32x4*)(ws + BOFF + (unsigned)nt*512u + (unsigned)nsub*16u)        = hi.v;
        *(f32x4*)(ws + BOFF + (unsigned)nt*512u + 256u + (unsigned)nsub*16u) = lo.v;
    }
    if (p < QTOT) {
        float a[8]; float xx = 0.f;
        #pragma unroll
        for (int d = 0; d < 5; ++d) { float x = rss[p*5+d]; a[d] = x; xx += x*x; }
        a[5] = -g * xx; a[6] = 1.0f; a[7] = 0.0f;
        union { ushort_t u[8]; f32x4 v; } hi, lo;
        #pragma unroll
        for (int k = 0; k < 8; ++k) bsplit(a[k], hi.u[k], lo.u[k]);
        *(f32x4*)(ws + AOFF + (unsigned)p*32u)       = hi.v;
        *(f32x4*)(ws + AOFF + (unsigned)p*32u + 16u) = lo.v;
    }
    if (p < 16)   *(f32x4*)(ws + ZOFF + (unsigned)p*16u) = (f32x4){0.f,0.f,0.f,0.f};
    if (p < ACCN) ((float*)(ws + ACCOFF))[p] = 0.0f;
    if (p == 0)   *(unsigned*)(ws + DONEOFF) = 0u;
}

// Main: wave = (qg, ns); 4 A-frags (64 q), sweep nt = ns, ns+NS, ...
// Per tile: 1x 16B/lane B load, 4 MFMA, 16 exp2, packed fp32 accum.
// C/D: col = lane&15 (n), row = (lane>>4)*4 + reg (q). Fin fused via counter.
__global__ __launch_bounds__(256, 4) void sknn_main(
    const char* __restrict__ tbl, const float* __restrict__ Loc,
    float* __restrict__ acc, unsigned* __restrict__ done,
    float* __restrict__ out)
{
    const int tid  = threadIdx.x;
    const int lane = tid & 63;
    const int wid  = (blockIdx.x * 256 + tid) >> 6;   // 0..4095
    const int qg   = wid >> 6;                        // 0..63
    const int ns   = wid & (NS - 1);                  // 0..63
    const int qbase = qg * 64;
    const int j  = lane & 15;
    const int qd = lane >> 4;

    // A frags: quadrants 0,1 -> Ah; 2 -> Al; 3 -> zeros
    const unsigned abase = (qd == 3) ? (ZOFF + (unsigned)j*16u)
        : (AOFF + (unsigned)(qbase + j)*32u + (qd == 2 ? 16u : 0u));
    const unsigned astep = (qd == 3) ? 0u : 512u;
    const s16x8 a0 = *(const s16x8*)(tbl + abase);
    const s16x8 a1 = *(const s16x8*)(tbl + abase + astep);
    const s16x8 a2 = *(const s16x8*)(tbl + abase + 2u*astep);
    const s16x8 a3 = *(const s16x8*)(tbl + abase + 3u*astep);

    // B stream: quadrants 0->Bh, 1->Bl, 2->Bh, 3->0
    unsigned bofs = (qd == 3) ? (ZOFF + (unsigned)j*16u)
        : (BOFF + (unsigned)ns*512u + (qd == 1 ? 256u : 0u) + (unsigned)j*16u);
    const unsigned bstep = (qd == 3) ? 0u : (512u * NS);

    unsigned lofs = (unsigned)(ns*16 + j) * 8u;       // lane's col n Loc (8B)
    const char* locb = (const char*)Loc;

    f2 sm2[8]; f2 o[16];
    #pragma unroll
    for (int k = 0; k < 8;  ++k) sm2[k] = (f2){0.f, 0.f};
    #pragma unroll
    for (int k = 0; k < 16; ++k) o[k]   = (f2){0.f, 0.f};
    const f32x4 zz = {0.f, 0.f, 0.f, 0.f};

    s16x8 bcur = *(const s16x8*)(tbl + bofs);
    f2    lcur = *(const f2*)(locb + lofs);

    for (int nt = ns; nt < NTILES; nt += NS) {
        const bool has = (nt + NS) < NTILES;
        const unsigned bn = bofs + (has ? bstep : 0u);
        const unsigned ln = lofs + (has ? (unsigned)(NS*16*8) : 0u);
        const s16x8 bnx = *(const s16x8*)(tbl + bn);
        const f2    lnx = *(const f2*)(locb + ln);

        f32x4 t[4];
        t[0] = __builtin_amdgcn_mfma_f32_16x16x32_bf16(a0, bcur, zz, 0, 0, 0);
        t[1] = __builtin_amdgcn_mfma_f32_16x16x32_bf16(a1, bcur, zz, 0, 0, 0);
        t[2] = __builtin_amdgcn_mfma_f32_16x16x32_bf16(a2, bcur, zz, 0, 0, 0);
        t[3] = __builtin_amdgcn_mfma_f32_16x16x32_bf16(a3, bcur, zz, 0, 0, 0);

        #pragma unroll
        for (int qt = 0; qt < 4; ++qt) {
            const float s0 = EXP2F(t[qt][0]);
            const float s1 = EXP2F(t[qt][1]);
            const float s2 = EXP2F(t[qt][2]);
            const float s3 = EXP2F(t[qt][3]);
            sm2[qt*2+0] += (f2){s0, s1};               // v_pk_add_f32
            sm2[qt*2+1] += (f2){s2, s3};
            o[qt*4+0] = fma2((f2){s0, s0}, lcur, o[qt*4+0]);  // v_pk_fma_f32
            o[qt*4+1] = fma2((f2){s1, s1}, lcur, o[qt*4+1]);
            o[qt*4+2] = fma2((f2){s2, s2}, lcur, o[qt*4+2]);
            o[qt*4+3] = fma2((f2){s3, s3}, lcur, o[qt*4+3]);
        }
        bcur = bnx; lcur = lnx; bofs = bn; lofs = ln;
    }

    // Butterfly reduce over each 16-lane column group
    #pragma unroll
    for (int m = 1; m <= 8; m <<= 1) {
        #pragma unroll
        for (int k = 0; k < 8; ++k) {
            sm2[k].x += __shfl_xor(sm2[k].x, m, 64);
            sm2[k].y += __shfl_xor(sm2[k].y, m, 64);
        }
        #pragma unroll
        for (int k = 0; k < 16; ++k) {
            o[k].x += __shfl_xor(o[k].x, m, 64);
            o[k].y += __shfl_xor(o[k].y, m, 64);
        }
    }

    #pragma unroll
    for (int qt = 0; qt < 4; ++qt) {
        #pragma unroll
        for (int i = 0; i < 4; ++i) {
            if (j == qt*4 + i) {
                const int q = qbase + qt*16 + qd*4 + i;
                const float sv = (i & 1) ? sm2[qt*2 + (i>>1)].y
                                         : sm2[qt*2 + (i>>1)].x;
                atomicAdd(&acc[q],          sv);
                atomicAdd(&acc[QTOT + q],   o[qt*4+i].x);
                atomicAdd(&acc[2*QTOT + q], o[qt*4+i].y);
            }
        }
    }

    // ---- fused finalize: last block divides ----
    __shared__ int lastFlag;
    __threadfence();                       // release our atomics (device scope)
    __syncthreads();
    if (tid == 0) {
        unsigned v = atomicAdd(done, 1u);
        lastFlag = (v == (unsigned)(MAINBLOCKS - 1));
    }
    __syncthreads();
    if (lastFlag) {
        __threadfence();                   // acquire
        for (int q = tid; q < QTOT; q += 256) {
            // agent-scope loads: bypass potentially-stale per-XCD cache copies
            const float s  = __hip_atomic_load(&acc[q],          __ATOMIC_RELAXED, __HIP_MEMORY_SCOPE_AGENT);
            const float w0 = __hip_atomic_load(&acc[QTOT + q],   __ATOMIC_RELAXED, __HIP_MEMORY_SCOPE_AGENT);
            const float w1 = __hip_atomic_load(&acc[2*QTOT + q], __ATOMIC_RELAXED, __HIP_MEMORY_SCOPE_AGENT);
            const float inv = 1.0f / s;
            out[q*2 + 0] = w0 * inv;
            out[q*2 + 1] = w1 * inv;
        }
    }
}

extern "C" void kernel_launch(void* const* d_in, const int* in_sizes, int n_in,
                              void* d_out, int out_size, void* d_ws, size_t ws_size,
                              hipStream_t stream) {
    const float* rss   = (const float*)d_in[0];
    const float* Radio = (const float*)d_in[1];
    const float* Loc   = (const float*)d_in[2];
    const float* sigma = (const float*)d_in[3];
    float* out = (float*)d_out;
    char*  ws  = (char*)d_ws;
    float*    acc  = (float*)(ws + ACCOFF);
    unsigned* done = (unsigned*)(ws + DONEOFF);

    sknn_prep<<<(NTOT + 255) / 256, dim3(256), 0, stream>>>(rss, Radio, sigma, ws);
    sknn_main<<<MAINBLOCKS, dim3(256), 0, stream>>>(ws, Loc, acc, done, out);
}

// Round 7
// 104.886 us; speedup vs baseline: 1.5801x; 1.5801x over previous
//
#include <hip/hip_runtime.h>
#include <hip/hip_bf16.h>
#include <math.h>

// Q=4096, N=50000, D=5, L=2
// t[q][n] = 2g*(x.r) - g|x|^2 - g|r|^2, g = log2e/(2 sigma^2);  s = 2^t
// K=8 augmented dot on the MFMA pipe, split-bf16 (hi+lo) packed into K=32:
//   A32 = [Ah|Ah|Al|0], B32 = [Bh|Bl|Bh|0] => Ah.Bh + Ah.Bl + Al.Bh
#define QTOT   4096
#define NTOT   50000
#define NTILES 3125            // 50000/16
#define NS     64              // n-phases; wave phase = nb*4 + waveid
#define NB     16              // n-blocks per q-group
#define QG     64              // q-groups (64 queries each)
#define MAINBLOCKS (QG * NB)   // 1024 blocks = 4096 waves = 4 blocks/CU

// ws layout (bytes)
#define BOFF   0u                          // B: [ntile][2][16][8 bf16] = 512 B/tile
#define BSIZE  (3125u * 512u)              // 1,600,000
#define AOFF   (BOFF + BSIZE)              // A: [q][2][8 bf16] = 32 B/q
#define ASIZE  (4096u * 32u)               // 131,072
#define ZOFF   (AOFF + ASIZE)              // 256 B zero block
#define PARTOFF (ZOFF + 256u)              // part: [NB][3][4096] f32 = 786,432 B

typedef unsigned short ushort_t;
typedef short  s16x8 __attribute__((ext_vector_type(8)));
typedef float  f32x4 __attribute__((ext_vector_type(4)));
typedef float  f2    __attribute__((ext_vector_type(2)));

#if __has_builtin(__builtin_amdgcn_exp2f)
#define EXP2F(x) __builtin_amdgcn_exp2f(x)
#else
#define EXP2F(x) exp2f(x)
#endif

static __device__ __forceinline__ f2 fma2(f2 a, f2 b, f2 c) {
#if __has_builtin(__builtin_elementwise_fma)
    return __builtin_elementwise_fma(a, b, c);
#else
    f2 r; r.x = fmaf(a.x, b.x, c.x); r.y = fmaf(a.y, b.y, c.y); return r;
#endif
}

static __device__ __forceinline__ void bsplit(float f, ushort_t& h, ushort_t& l) {
    __hip_bfloat16 hb = __float2bfloat16(f);
    float hf = __bfloat162float(hb);
    __hip_bfloat16 lb = __float2bfloat16(f - hf);
    h = *reinterpret_cast<ushort_t*>(&hb);
    l = *reinterpret_cast<ushort_t*>(&lb);
}

__global__ __launch_bounds__(256) void sknn_prep(
    const float* __restrict__ rss, const float* __restrict__ Radio,
    const float* __restrict__ sigma, char* __restrict__ ws)
{
    const int p = blockIdx.x * 256 + threadIdx.x;
    const float sg = sigma[0];
    const float g  = 1.4426950408889634f / (2.0f * sg * sg);
    const float g2 = 2.0f * g;

    if (p < NTOT) {
        float b[8]; float rr = 0.f;
        #pragma unroll
        for (int d = 0; d < 5; ++d) { float r = Radio[p*5+d]; b[d] = g2*r; rr += r*r; }
        b[5] = 1.0f; b[6] = -g * rr; b[7] = 0.0f;
        union { ushort_t u[8]; f32x4 v; } hi, lo;
        #pragma unroll
        for (int k = 0; k < 8; ++k) bsplit(b[k], hi.u[k], lo.u[k]);
        const int nt = p >> 4, nsub = p & 15;
        *(f32x4*)(ws + BOFF + (unsigned)nt*512u + (unsigned)nsub*16u)        = hi.v;
        *(f32x4*)(ws + BOFF + (unsigned)nt*512u + 256u + (unsigned)nsub*16u) = lo.v;
    }
    if (p < QTOT) {
        float a[8]; float xx = 0.f;
        #pragma unroll
        for (int d = 0; d < 5; ++d) { float x = rss[p*5+d]; a[d] = x; xx += x*x; }
        a[5] = -g * xx; a[6] = 1.0f; a[7] = 0.0f;
        union { ushort_t u[8]; f32x4 v; } hi, lo;
        #pragma unroll
        for (int k = 0; k < 8; ++k) bsplit(a[k], hi.u[k], lo.u[k]);
        *(f32x4*)(ws + AOFF + (unsigned)p*32u)       = hi.v;
        *(f32x4*)(ws + AOFF + (unsigned)p*32u + 16u) = lo.v;
    }
    if (p < 16) *(f32x4*)(ws + ZOFF + (unsigned)p*16u) = (f32x4){0.f,0.f,0.f,0.f};
}

// Main: block = (qg, nb); its 4 waves share the q-group, phases ns = nb*4+w.
// Per n-tile: 1x 16B/lane B load, 4 MFMA, 16 exp2, packed fp32 accum.
// C/D: col = lane&15 (n), row = (lane>>4)*4 + reg (q).
// Reduction: in-wave butterfly -> 3 KB LDS across the 4 waves -> 192 plain
// coalesced stores of block partials (NO atomics, NO fences anywhere).
__global__ __launch_bounds__(256, 4) void sknn_main(
    const char* __restrict__ tbl, const float* __restrict__ Loc,
    float* __restrict__ part)
{
    const int tid  = threadIdx.x;
    const int lane = tid & 63;
    const int w    = tid >> 6;                        // wave in block: 0..3
    const int qg   = blockIdx.x & (QG - 1);           // 0..63
    const int nb   = blockIdx.x >> 6;                 // 0..15
    const int ns   = nb * 4 + w;                      // phase 0..63
    const int qbase = qg * 64;
    const int j  = lane & 15;
    const int qd = lane >> 4;

    // A frags: quadrants 0,1 -> Ah; 2 -> Al; 3 -> zeros
    const unsigned abase = (qd == 3) ? (ZOFF + (unsigned)j*16u)
        : (AOFF + (unsigned)(qbase + j)*32u + (qd == 2 ? 16u : 0u));
    const unsigned astep = (qd == 3) ? 0u : 512u;
    const s16x8 a0 = *(const s16x8*)(tbl + abase);
    const s16x8 a1 = *(const s16x8*)(tbl + abase + astep);
    const s16x8 a2 = *(const s16x8*)(tbl + abase + 2u*astep);
    const s16x8 a3 = *(const s16x8*)(tbl + abase + 3u*astep);

    // B stream: quadrants 0->Bh, 1->Bl, 2->Bh, 3->0
    unsigned bofs = (qd == 3) ? (ZOFF + (unsigned)j*16u)
        : (BOFF + (unsigned)ns*512u + (qd == 1 ? 256u : 0u) + (unsigned)j*16u);
    const unsigned bstep = (qd == 3) ? 0u : (512u * NS);

    unsigned lofs = (unsigned)(ns*16 + j) * 8u;       // lane's col-n Loc (8B)
    const char* locb = (const char*)Loc;

    f2 sm2[8]; f2 o[16];
    #pragma unroll
    for (int k = 0; k < 8;  ++k) sm2[k] = (f2){0.f, 0.f};
    #pragma unroll
    for (int k = 0; k < 16; ++k) o[k]   = (f2){0.f, 0.f};
    const f32x4 zz = {0.f, 0.f, 0.f, 0.f};

    s16x8 bcur = *(const s16x8*)(tbl + bofs);
    f2    lcur = *(const f2*)(locb + lofs);

    for (int nt = ns; nt < NTILES; nt += NS) {
        const bool has = (nt + NS) < NTILES;
        const unsigned bn = bofs + (has ? bstep : 0u);
        const unsigned ln = lofs + (has ? (unsigned)(NS*16*8) : 0u);
        const s16x8 bnx = *(const s16x8*)(tbl + bn);   // prefetch next tile
        const f2    lnx = *(const f2*)(locb + ln);

        f32x4 t[4];
        t[0] = __builtin_amdgcn_mfma_f32_16x16x32_bf16(a0, bcur, zz, 0, 0, 0);
        t[1] = __builtin_amdgcn_mfma_f32_16x16x32_bf16(a1, bcur, zz, 0, 0, 0);
        t[2] = __builtin_amdgcn_mfma_f32_16x16x32_bf16(a2, bcur, zz, 0, 0, 0);
        t[3] = __builtin_amdgcn_mfma_f32_16x16x32_bf16(a3, bcur, zz, 0, 0, 0);

        #pragma unroll
        for (int qt = 0; qt < 4; ++qt) {
            const float s0 = EXP2F(t[qt][0]);
            const float s1 = EXP2F(t[qt][1]);
            const float s2 = EXP2F(t[qt][2]);
            const float s3 = EXP2F(t[qt][3]);
            sm2[qt*2+0] += (f2){s0, s1};
            sm2[qt*2+1] += (f2){s2, s3};
            o[qt*4+0] = fma2((f2){s0, s0}, lcur, o[qt*4+0]);
            o[qt*4+1] = fma2((f2){s1, s1}, lcur, o[qt*4+1]);
            o[qt*4+2] = fma2((f2){s2, s2}, lcur, o[qt*4+2]);
            o[qt*4+3] = fma2((f2){s3, s3}, lcur, o[qt*4+3]);
        }
        bcur = bnx; lcur = lnx; bofs = bn; lofs = ln;
    }

    // In-wave butterfly over each 16-lane column group
    #pragma unroll
    for (int m = 1; m <= 8; m <<= 1) {
        #pragma unroll
        for (int k = 0; k < 8; ++k) {
            sm2[k].x += __shfl_xor(sm2[k].x, m, 64);
            sm2[k].y += __shfl_xor(sm2[k].y, m, 64);
        }
        #pragma unroll
        for (int k = 0; k < 16; ++k) {
            o[k].x += __shfl_xor(o[k].x, m, 64);
            o[k].y += __shfl_xor(o[k].y, m, 64);
        }
    }

    // Cross-wave reduction in LDS: red[wave][comp][q_local]
    __shared__ float red[4][3][64];
    #pragma unroll
    for (int qt = 0; qt < 4; ++qt) {
        #pragma unroll
        for (int i = 0; i < 4; ++i) {
            if (j == qt*4 + i) {
                const int ql = qt*16 + qd*4 + i;
                red[w][0][ql] = (i & 1) ? sm2[qt*2 + (i>>1)].y
                                        : sm2[qt*2 + (i>>1)].x;
                red[w][1][ql] = o[qt*4+i].x;
                red[w][2][ql] = o[qt*4+i].y;
            }
        }
    }
    __syncthreads();

    // 192 threads: sum 4 waves, one plain coalesced store each.
    if (tid < 192) {
        const int comp = tid >> 6, ql = tid & 63;
        const float v = red[0][comp][ql] + red[1][comp][ql]
                      + red[2][comp][ql] + red[3][comp][ql];
        part[((nb * 3 + comp) << 12) + qbase + ql] = v;
    }
}

__global__ __launch_bounds__(256) void sknn_fin(
    const float* __restrict__ part, float* __restrict__ out)
{
    const int q = blockIdx.x * 256 + threadIdx.x;   // 16 blocks cover 4096
    float s = 0.f, w0 = 0.f, w1 = 0.f;
    #pragma unroll
    for (int nb = 0; nb < NB; ++nb) {
        s  += part[((nb * 3 + 0) << 12) + q];
        w0 += part[((nb * 3 + 1) << 12) + q];
        w1 += part[((nb * 3 + 2) << 12) + q];
    }
    const float inv = 1.0f / s;
    out[q * 2 + 0] = w0 * inv;
    out[q * 2 + 1] = w1 * inv;
}

extern "C" void kernel_launch(void* const* d_in, const int* in_sizes, int n_in,
                              void* d_out, int out_size, void* d_ws, size_t ws_size,
                              hipStream_t stream) {
    const float* rss   = (const float*)d_in[0];
    const float* Radio = (const float*)d_in[1];
    const float* Loc   = (const float*)d_in[2];
    const float* sigma = (const float*)d_in[3];
    float* out  = (float*)d_out;
    char*  ws   = (char*)d_ws;
    float* part = (float*)(ws + PARTOFF);

    sknn_prep<<<(NTOT + 255) / 256, dim3(256), 0, stream>>>(rss, Radio, sigma, ws);
    sknn_main<<<MAINBLOCKS, dim3(256), 0, stream>>>(ws, Loc, part);
    sknn_fin<<<QTOT / 256, dim3(256), 0, stream>>>(part, out);
}

// Round 10
// 98.900 us; speedup vs baseline: 1.6758x; 1.0605x over previous
//
#include <hip/hip_runtime.h>
#include <hip/hip_bf16.h>
#include <math.h>

// Q=4096, N=50000, D=5, L=2
// t[q][n] = 2g*(x.r) - g|x|^2 - g|r|^2, g = log2e/(2 sigma^2);  s = 2^t
// K=8 augmented dot on the MFMA pipe, split-bf16 (hi+lo) packed into K=32:
//   A32 = [Ah|Ah|Al|0], B32 = [Bh|Bl|Bh|0] => Ah.Bh + Ah.Bl + Al.Bh
#define QTOT   4096
#define NTOT   50000
#define NTILES 3125            // 50000/16
#define NS     64              // n-phases; wave phase = nb*4 + waveid
#define NB     16              // n-blocks per q-group
#define QG     64              // q-groups (64 queries each)
#define MAINBLOCKS (QG * NB)   // 1024 blocks = 4096 waves = 4 blocks/CU
#define LSTEP  (NS * 16 * 8)   // Loc stream stride per iteration (bytes)

// ws layout (bytes) — identical to the R7 layout that passed
#define BOFF   0u                          // B: [ntile][2][16][8 bf16] = 512 B/tile
#define BSIZE  (3125u * 512u)              // 1,600,000
#define AOFF   (BOFF + BSIZE)              // A: [q][2][8 bf16] = 32 B/q
#define ASIZE  (4096u * 32u)               // 131,072
#define ZOFF   (AOFF + ASIZE)              // 256 B zero block
#define PARTOFF (ZOFF + 256u)              // part: [NB][3][4096] f32 = 786,432 B

typedef unsigned short ushort_t;
typedef short  s16x8 __attribute__((ext_vector_type(8)));
typedef float  f32x4 __attribute__((ext_vector_type(4)));
typedef float  f2    __attribute__((ext_vector_type(2)));

#if __has_builtin(__builtin_amdgcn_exp2f)
#define EXP2F(x) __builtin_amdgcn_exp2f(x)
#else
#define EXP2F(x) exp2f(x)
#endif

static __device__ __forceinline__ f2 fma2(f2 a, f2 b, f2 c) {
#if __has_builtin(__builtin_elementwise_fma)
    return __builtin_elementwise_fma(a, b, c);
#else
    f2 r; r.x = fmaf(a.x, b.x, c.x); r.y = fmaf(a.y, b.y, c.y); return r;
#endif
}

static __device__ __forceinline__ void bsplit(float f, ushort_t& h, ushort_t& l) {
    __hip_bfloat16 hb = __float2bfloat16(f);
    float hf = __bfloat162float(hb);
    __hip_bfloat16 lb = __float2bfloat16(f - hf);
    h = *reinterpret_cast<ushort_t*>(&hb);
    l = *reinterpret_cast<ushort_t*>(&lb);
}

__global__ __launch_bounds__(256) void sknn_prep(
    const float* __restrict__ rss, const float* __restrict__ Radio,
    const float* __restrict__ sigma, char* __restrict__ ws)
{
    const int p = blockIdx.x * 256 + threadIdx.x;
    const float sg = sigma[0];
    const float g  = 1.4426950408889634f / (2.0f * sg * sg);
    const float g2 = 2.0f * g;

    if (p < NTOT) {
        float b[8]; float rr = 0.f;
        #pragma unroll
        for (int d = 0; d < 5; ++d) { float r = Radio[p*5+d]; b[d] = g2*r; rr += r*r; }
        b[5] = 1.0f; b[6] = -g * rr; b[7] = 0.0f;
        union { ushort_t u[8]; f32x4 v; } hi, lo;
        #pragma unroll
        for (int k = 0; k < 8; ++k) bsplit(b[k], hi.u[k], lo.u[k]);
        const int nt = p >> 4, nsub = p & 15;
        *(f32x4*)(ws + BOFF + (unsigned)nt*512u + (unsigned)nsub*16u)        = hi.v;
        *(f32x4*)(ws + BOFF + (unsigned)nt*512u + 256u + (unsigned)nsub*16u) = lo.v;
    }
    if (p < QTOT) {
        float a[8]; float xx = 0.f;
        #pragma unroll
        for (int d = 0; d < 5; ++d) { float x = rss[p*5+d]; a[d] = x; xx += x*x; }
        a[5] = -g * xx; a[6] = 1.0f; a[7] = 0.0f;
        union { ushort_t u[8]; f32x4 v; } hi, lo;
        #pragma unroll
        for (int k = 0; k < 8; ++k) bsplit(a[k], hi.u[k], lo.u[k]);
        *(f32x4*)(ws + AOFF + (unsigned)p*32u)       = hi.v;
        *(f32x4*)(ws + AOFF + (unsigned)p*32u + 16u) = lo.v;
    }
    if (p < 16) *(f32x4*)(ws + ZOFF + (unsigned)p*16u) = (f32x4){0.f,0.f,0.f,0.f};
}

// Main: block = (qg, nb); 4 waves share the q-group, phases ns = nb*4+w.
// nb = blockIdx & 15 -> XCD (blockIdx%8) only streams 8 of 64 phases
// (~250 KB of B+Loc per XCD L2, resident).
// Per n-tile: 1x 16B/lane B load, 4 MFMA, 16 exp2, fp32 accum (compiler-
// scheduled scalar ops — R7-verbatim; the R8/R9 pk-asm path miscompiled).
// K-loop peeled: 48 hot iters with unconditional prefetch + final iter.
// C/D: col = lane&15 (n), row = (lane>>4)*4 + reg (q).
__global__ __launch_bounds__(256, 4) void sknn_main(
    const char* __restrict__ tbl, const float* __restrict__ Loc,
    float* __restrict__ part)
{
    const int tid  = threadIdx.x;
    const int lane = tid & 63;
    const int w    = tid >> 6;                        // wave in block: 0..3
    const int nb   = blockIdx.x & (NB - 1);           // 0..15 (XCD swizzle)
    const int qg   = blockIdx.x >> 4;                 // 0..63
    const int ns   = nb * 4 + w;                      // phase 0..63
    const int qbase = qg * 64;
    const int j  = lane & 15;
    const int qd = lane >> 4;

    // A frags: quadrants 0,1 -> Ah; 2 -> Al; 3 -> zeros
    const unsigned abase = (qd == 3) ? (ZOFF + (unsigned)j*16u)
        : (AOFF + (unsigned)(qbase + j)*32u + (qd == 2 ? 16u : 0u));
    const unsigned astep = (qd == 3) ? 0u : 512u;
    const s16x8 a0 = *(const s16x8*)(tbl + abase);
    const s16x8 a1 = *(const s16x8*)(tbl + abase + astep);
    const s16x8 a2 = *(const s16x8*)(tbl + abase + 2u*astep);
    const s16x8 a3 = *(const s16x8*)(tbl + abase + 3u*astep);

    // B stream: quadrants 0->Bh, 1->Bl, 2->Bh, 3->0
    unsigned bofs = (qd == 3) ? (ZOFF + (unsigned)j*16u)
        : (BOFF + (unsigned)ns*512u + (qd == 1 ? 256u : 0u) + (unsigned)j*16u);
    const unsigned bstep = (qd == 3) ? 0u : (512u * NS);

    unsigned lofs = (unsigned)(ns*16 + j) * 8u;       // lane's col-n Loc (8B)
    const char* locb = (const char*)Loc;

    f2 sm2[8]; f2 o[16];
    #pragma unroll
    for (int k = 0; k < 8;  ++k) sm2[k] = (f2){0.f, 0.f};
    #pragma unroll
    for (int k = 0; k < 16; ++k) o[k]   = (f2){0.f, 0.f};
    const f32x4 zz = {0.f, 0.f, 0.f, 0.f};

    s16x8 bcur = *(const s16x8*)(tbl + bofs);
    f2    lcur = *(const f2*)(locb + lofs);

    int nt = ns;
    // hot loop: guaranteed next tile -> unconditional prefetch, no guards
    while (nt + NS < NTILES) {
        bofs += bstep;
        lofs += (unsigned)LSTEP;
        const s16x8 bnx = *(const s16x8*)(tbl + bofs);
        const f2    lnx = *(const f2*)(locb + lofs);

        f32x4 t[4];
        t[0] = __builtin_amdgcn_mfma_f32_16x16x32_bf16(a0, bcur, zz, 0, 0, 0);
        t[1] = __builtin_amdgcn_mfma_f32_16x16x32_bf16(a1, bcur, zz, 0, 0, 0);
        t[2] = __builtin_amdgcn_mfma_f32_16x16x32_bf16(a2, bcur, zz, 0, 0, 0);
        t[3] = __builtin_amdgcn_mfma_f32_16x16x32_bf16(a3, bcur, zz, 0, 0, 0);

        #pragma unroll
        for (int qt = 0; qt < 4; ++qt) {
            const float s0 = EXP2F(t[qt][0]);
            const float s1 = EXP2F(t[qt][1]);
            const float s2 = EXP2F(t[qt][2]);
            const float s3 = EXP2F(t[qt][3]);
            sm2[qt*2+0] += (f2){s0, s1};
            sm2[qt*2+1] += (f2){s2, s3};
            o[qt*4+0] = fma2((f2){s0, s0}, lcur, o[qt*4+0]);
            o[qt*4+1] = fma2((f2){s1, s1}, lcur, o[qt*4+1]);
            o[qt*4+2] = fma2((f2){s2, s2}, lcur, o[qt*4+2]);
            o[qt*4+3] = fma2((f2){s3, s3}, lcur, o[qt*4+3]);
        }
        bcur = bnx; lcur = lnx;
        nt += NS;
    }
    // final tile (no prefetch)
    {
        f32x4 t[4];
        t[0] = __builtin_amdgcn_mfma_f32_16x16x32_bf16(a0, bcur, zz, 0, 0, 0);
        t[1] = __builtin_amdgcn_mfma_f32_16x16x32_bf16(a1, bcur, zz, 0, 0, 0);
        t[2] = __builtin_amdgcn_mfma_f32_16x16x32_bf16(a2, bcur, zz, 0, 0, 0);
        t[3] = __builtin_amdgcn_mfma_f32_16x16x32_bf16(a3, bcur, zz, 0, 0, 0);

        #pragma unroll
        for (int qt = 0; qt < 4; ++qt) {
            const float s0 = EXP2F(t[qt][0]);
            const float s1 = EXP2F(t[qt][1]);
            const float s2 = EXP2F(t[qt][2]);
            const float s3 = EXP2F(t[qt][3]);
            sm2[qt*2+0] += (f2){s0, s1};
            sm2[qt*2+1] += (f2){s2, s3};
            o[qt*4+0] = fma2((f2){s0, s0}, lcur, o[qt*4+0]);
            o[qt*4+1] = fma2((f2){s1, s1}, lcur, o[qt*4+1]);
            o[qt*4+2] = fma2((f2){s2, s2}, lcur, o[qt*4+2]);
            o[qt*4+3] = fma2((f2){s3, s3}, lcur, o[qt*4+3]);
        }
    }

    // In-wave butterfly over each 16-lane column group
    #pragma unroll
    for (int m = 1; m <= 8; m <<= 1) {
        #pragma unroll
        for (int k = 0; k < 8; ++k) {
            sm2[k].x += __shfl_xor(sm2[k].x, m, 64);
            sm2[k].y += __shfl_xor(sm2[k].y, m, 64);
        }
        #pragma unroll
        for (int k = 0; k < 16; ++k) {
            o[k].x += __shfl_xor(o[k].x, m, 64);
            o[k].y += __shfl_xor(o[k].y, m, 64);
        }
    }

    // Cross-wave reduction in LDS: red[wave][comp][q_local]
    __shared__ float red[4][3][64];
    #pragma unroll
    for (int qt = 0; qt < 4; ++qt) {
        #pragma unroll
        for (int i = 0; i < 4; ++i) {
            if (j == qt*4 + i) {
                const int ql = qt*16 + qd*4 + i;
                red[w][0][ql] = (i & 1) ? sm2[qt*2 + (i>>1)].y
                                        : sm2[qt*2 + (i>>1)].x;
                red[w][1][ql] = o[qt*4+i].x;
                red[w][2][ql] = o[qt*4+i].y;
            }
        }
    }
    __syncthreads();

    // 192 threads: sum 4 waves, one plain coalesced store each (no atomics).
    if (tid < 192) {
        const int comp = tid >> 6, ql = tid & 63;
        const float v = red[0][comp][ql] + red[1][comp][ql]
                      + red[2][comp][ql] + red[3][comp][ql];
        part[((nb * 3 + comp) << 12) + qbase + ql] = v;
    }
}

__global__ __launch_bounds__(256) void sknn_fin(
    const float* __restrict__ part, float* __restrict__ out)
{
    const int q = blockIdx.x * 256 + threadIdx.x;   // 16 blocks cover 4096
    float s = 0.f, w0 = 0.f, w1 = 0.f;
    #pragma unroll
    for (int nb = 0; nb < NB; ++nb) {
        s  += part[((nb * 3 + 0) << 12) + q];
        w0 += part[((nb * 3 + 1) << 12) + q];
        w1 += part[((nb * 3 + 2) << 12) + q];
    }
    const float inv = 1.0f / s;
    out[q * 2 + 0] = w0 * inv;
    out[q * 2 + 1] = w1 * inv;
}

extern "C" void kernel_launch(void* const* d_in, const int* in_sizes, int n_in,
                              void* d_out, int out_size, void* d_ws, size_t ws_size,
                              hipStream_t stream) {
    const float* rss   = (const float*)d_in[0];
    const float* Radio = (const float*)d_in[1];
    const float* Loc   = (const float*)d_in[2];
    const float* sigma = (const float*)d_in[3];
    float* out  = (float*)d_out;
    char*  ws   = (char*)d_ws;
    float* part = (float*)(ws + PARTOFF);

    sknn_prep<<<(NTOT + 255) / 256, dim3(256), 0, stream>>>(rss, Radio, sigma, ws);
    sknn_main<<<MAINBLOCKS, dim3(256), 0, stream>>>(ws, Loc, part);
    sknn_fin<<<QTOT / 256, dim3(256), 0, stream>>>(part, out);
}

// Round 11
// 98.127 us; speedup vs baseline: 1.6890x; 1.0079x over previous
//
#include <hip/hip_runtime.h>
#include <hip/hip_bf16.h>
#include <math.h>

// Q=4096, N=50000, D=5, L=2
// t[q][n] = 2g*(x.r) - g|x|^2 - g|r|^2, g = log2e/(2 sigma^2);  s = 2^t
// K=8 augmented dot on the MFMA pipe, split-bf16 (hi+lo) packed into K=32:
//   A32 = [Ah|Ah|Al|0], B32 = [Bh|Bl|Bh|0] => Ah.Bh + Ah.Bl + Al.Bh
#define QTOT   4096
#define NTOT   50000
#define NTILES 3125            // 50000/16
#define NS     64              // n-phases; wave phase = nb*4 + waveid
#define NB     16              // n-blocks per q-slice
#define QH     128             // q-slices of 32 queries (2 tiles) each
#define MAINBLOCKS (QH * NB)   // 2048 blocks = 8192 waves = 8 blocks/CU (32 waves/CU cap)
#define LSTEP  (NS * 16 * 8)   // Loc stream stride per iteration (bytes)

// ws layout (bytes) — identical to the R7/R10 layout that passed (2.52 MB)
#define BOFF   0u                          // B: [ntile][2][16][8 bf16] = 512 B/tile
#define BSIZE  (3125u * 512u)              // 1,600,000
#define AOFF   (BOFF + BSIZE)              // A: [q][2][8 bf16] = 32 B/q
#define ASIZE  (4096u * 32u)               // 131,072
#define ZOFF   (AOFF + ASIZE)              // 256 B zero block
#define PARTOFF (ZOFF + 256u)              // part: [NB][3][4096] f32 = 786,432 B

typedef unsigned short ushort_t;
typedef short  s16x8 __attribute__((ext_vector_type(8)));
typedef float  f32x4 __attribute__((ext_vector_type(4)));
typedef float  f2    __attribute__((ext_vector_type(2)));

#if __has_builtin(__builtin_amdgcn_exp2f)
#define EXP2F(x) __builtin_amdgcn_exp2f(x)
#else
#define EXP2F(x) exp2f(x)
#endif

static __device__ __forceinline__ void bsplit(float f, ushort_t& h, ushort_t& l) {
    __hip_bfloat16 hb = __float2bfloat16(f);
    float hf = __bfloat162float(hb);
    __hip_bfloat16 lb = __float2bfloat16(f - hf);
    h = *reinterpret_cast<ushort_t*>(&hb);
    l = *reinterpret_cast<ushort_t*>(&lb);
}

__global__ __launch_bounds__(256) void sknn_prep(
    const float* __restrict__ rss, const float* __restrict__ Radio,
    const float* __restrict__ sigma, char* __restrict__ ws)
{
    const int p = blockIdx.x * 256 + threadIdx.x;
    const float sg = sigma[0];
    const float g  = 1.4426950408889634f / (2.0f * sg * sg);
    const float g2 = 2.0f * g;

    if (p < NTOT) {
        float b[8]; float rr = 0.f;
        #pragma unroll
        for (int d = 0; d < 5; ++d) { float r = Radio[p*5+d]; b[d] = g2*r; rr += r*r; }
        b[5] = 1.0f; b[6] = -g * rr; b[7] = 0.0f;
        union { ushort_t u[8]; f32x4 v; } hi, lo;
        #pragma unroll
        for (int k = 0; k < 8; ++k) bsplit(b[k], hi.u[k], lo.u[k]);
        const int nt = p >> 4, nsub = p & 15;
        *(f32x4*)(ws + BOFF + (unsigned)nt*512u + (unsigned)nsub*16u)        = hi.v;
        *(f32x4*)(ws + BOFF + (unsigned)nt*512u + 256u + (unsigned)nsub*16u) = lo.v;
    }
    if (p < QTOT) {
        float a[8]; float xx = 0.f;
        #pragma unroll
        for (int d = 0; d < 5; ++d) { float x = rss[p*5+d]; a[d] = x; xx += x*x; }
        a[5] = -g * xx; a[6] = 1.0f; a[7] = 0.0f;
        union { ushort_t u[8]; f32x4 v; } hi, lo;
        #pragma unroll
        for (int k = 0; k < 8; ++k) bsplit(a[k], hi.u[k], lo.u[k]);
        *(f32x4*)(ws + AOFF + (unsigned)p*32u)       = hi.v;
        *(f32x4*)(ws + AOFF + (unsigned)p*32u + 16u) = lo.v;
    }
    if (p < 16) *(f32x4*)(ws + ZOFF + (unsigned)p*16u) = (f32x4){0.f,0.f,0.f,0.f};
}

// Main: block = (qh, nb); 4 waves share the 32-query slice, phases ns = nb*4+w.
// nb = blockIdx & 15 -> XCD (blockIdx%8) streams a localized B/Loc slice.
// 8 blocks/CU = 32 waves/CU (HW cap) for latency hiding.
// Per n-tile: 1x 16B/lane B load, 2 MFMA, 8 exp2, 24 scalar fma/add.
// C/D: col = lane&15 (ref n), row = (lane>>4)*4 + reg (query).
__global__ __launch_bounds__(256, 8) void sknn_main(
    const char* __restrict__ tbl, const float* __restrict__ Loc,
    float* __restrict__ part)
{
    const int tid  = threadIdx.x;
    const int lane = tid & 63;
    const int w    = tid >> 6;                        // wave in block: 0..3
    const int nb   = blockIdx.x & (NB - 1);           // 0..15 (XCD swizzle)
    const int qh   = blockIdx.x >> 4;                 // 0..127
    const int ns   = nb * 4 + w;                      // phase 0..63
    const int qbase = qh * 32;
    const int j  = lane & 15;
    const int qd = lane >> 4;

    // A frags (2 q-tiles): quadrants 0,1 -> Ah; 2 -> Al; 3 -> zeros
    const unsigned abase = (qd == 3) ? (ZOFF + (unsigned)j*16u)
        : (AOFF + (unsigned)(qbase + j)*32u + (qd == 2 ? 16u : 0u));
    const unsigned astep = (qd == 3) ? 0u : 512u;     // 16 queries * 32 B
    const s16x8 a0 = *(const s16x8*)(tbl + abase);
    const s16x8 a1 = *(const s16x8*)(tbl + abase + astep);

    // B stream: quadrants 0->Bh, 1->Bl, 2->Bh, 3->0
    unsigned bofs = (qd == 3) ? (ZOFF + (unsigned)j*16u)
        : (BOFF + (unsigned)ns*512u + (qd == 1 ? 256u : 0u) + (unsigned)j*16u);
    const unsigned bstep = (qd == 3) ? 0u : (512u * NS);

    unsigned lofs = (unsigned)(ns*16 + j) * 8u;       // lane's col-n Loc (8B)
    const char* locb = (const char*)Loc;

    float sm[8], o0[8], o1[8];
    #pragma unroll
    for (int k = 0; k < 8; ++k) { sm[k] = 0.f; o0[k] = 0.f; o1[k] = 0.f; }
    const f32x4 zz = {0.f, 0.f, 0.f, 0.f};

    s16x8 bcur = *(const s16x8*)(tbl + bofs);
    f2    lcur = *(const f2*)(locb + lofs);

    int nt = ns;
    // hot loop: guaranteed next tile -> unconditional prefetch, no guards
    while (nt + NS < NTILES) {
        bofs += bstep;
        lofs += (unsigned)LSTEP;
        const s16x8 bnx = *(const s16x8*)(tbl + bofs);
        const f2    lnx = *(const f2*)(locb + lofs);

        f32x4 t[2];
        t[0] = __builtin_amdgcn_mfma_f32_16x16x32_bf16(a0, bcur, zz, 0, 0, 0);
        t[1] = __builtin_amdgcn_mfma_f32_16x16x32_bf16(a1, bcur, zz, 0, 0, 0);

        #pragma unroll
        for (int qt = 0; qt < 2; ++qt) {
            #pragma unroll
            for (int i = 0; i < 4; ++i) {
                const float s = EXP2F(t[qt][i]);
                sm[qt*4+i] += s;
                o0[qt*4+i] = fmaf(s, lcur.x, o0[qt*4+i]);
                o1[qt*4+i] = fmaf(s, lcur.y, o1[qt*4+i]);
            }
        }
        bcur = bnx; lcur = lnx;
        nt += NS;
    }
    // final tile (no prefetch)
    {
        f32x4 t[2];
        t[0] = __builtin_amdgcn_mfma_f32_16x16x32_bf16(a0, bcur, zz, 0, 0, 0);
        t[1] = __builtin_amdgcn_mfma_f32_16x16x32_bf16(a1, bcur, zz, 0, 0, 0);

        #pragma unroll
        for (int qt = 0; qt < 2; ++qt) {
            #pragma unroll
            for (int i = 0; i < 4; ++i) {
                const float s = EXP2F(t[qt][i]);
                sm[qt*4+i] += s;
                o0[qt*4+i] = fmaf(s, lcur.x, o0[qt*4+i]);
                o1[qt*4+i] = fmaf(s, lcur.y, o1[qt*4+i]);
            }
        }
    }

    // In-wave butterfly over each 16-lane column (ref) group
    #pragma unroll
    for (int m = 1; m <= 8; m <<= 1) {
        #pragma unroll
        for (int k = 0; k < 8; ++k) {
            sm[k] += __shfl_xor(sm[k], m, 64);
            o0[k] += __shfl_xor(o0[k], m, 64);
            o1[k] += __shfl_xor(o1[k], m, 64);
        }
    }

    // Cross-wave reduction in LDS: red[wave][comp][q_local]
    __shared__ float red[4][3][32];
    #pragma unroll
    for (int qt = 0; qt < 2; ++qt) {
        #pragma unroll
        for (int i = 0; i < 4; ++i) {
            if (j == qt*4 + i) {
                const int ql = qt*16 + qd*4 + i;
                red[w][0][ql] = sm[qt*4+i];
                red[w][1][ql] = o0[qt*4+i];
                red[w][2][ql] = o1[qt*4+i];
            }
        }
    }
    __syncthreads();

    // 96 threads: sum 4 waves, one plain coalesced store each (no atomics).
    if (tid < 96) {
        const int comp = tid >> 5, ql = tid & 31;
        const float v = red[0][comp][ql] + red[1][comp][ql]
                      + red[2][comp][ql] + red[3][comp][ql];
        part[((nb * 3 + comp) << 12) + qbase + ql] = v;
    }
}

__global__ __launch_bounds__(256) void sknn_fin(
    const float* __restrict__ part, float* __restrict__ out)
{
    const int q = blockIdx.x * 256 + threadIdx.x;   // 16 blocks cover 4096
    float s = 0.f, w0 = 0.f, w1 = 0.f;
    #pragma unroll
    for (int nb = 0; nb < NB; ++nb) {
        s  += part[((nb * 3 + 0) << 12) + q];
        w0 += part[((nb * 3 + 1) << 12) + q];
        w1 += part[((nb * 3 + 2) << 12) + q];
    }
    const float inv = 1.0f / s;
    out[q * 2 + 0] = w0 * inv;
    out[q * 2 + 1] = w1 * inv;
}

extern "C" void kernel_launch(void* const* d_in, const int* in_sizes, int n_in,
                              void* d_out, int out_size, void* d_ws, size_t ws_size,
                              hipStream_t stream) {
    const float* rss   = (const float*)d_in[0];
    const float* Radio = (const float*)d_in[1];
    const float* Loc   = (const float*)d_in[2];
    const float* sigma = (const float*)d_in[3];
    float* out  = (float*)d_out;
    char*  ws   = (char*)d_ws;
    float* part = (float*)(ws + PARTOFF);

    sknn_prep<<<(NTOT + 255) / 256, dim3(256), 0, stream>>>(rss, Radio, sigma, ws);
    sknn_main<<<MAINBLOCKS, dim3(256), 0, stream>>>(ws, Loc, part);
    sknn_fin<<<QTOT / 256, dim3(256), 0, stream>>>(part, out);
}